// Round 16
// baseline (155.176 us; speedup 1.0000x reference)
//
#include <hip/hip_runtime.h>

// MultiHeadVectorAttention — round 16: D/V and agg stored as single-rne bf16
// (halves projM/agg writes, halves attn gather bytes, outM 2-pass).
// All sync/layout/indexing identical to round-15 verified kernels.
// bs=2, n=1024, H=8, DH=64, K=16, EMB=INNER=512, AINNER=256, POSH=64.

#define BS 2
#define NPT 1024
#define HH 8
#define DH 64
#define KNN 16
#define EMB 512
#define INNER 512
#define AINNER 256
#define POSH 64

typedef unsigned short u16;
typedef unsigned int u32;
typedef __attribute__((ext_vector_type(8))) short bf16x8;
typedef __attribute__((ext_vector_type(4))) float f32x4;

__device__ __forceinline__ float bf2f(u16 b) { union { u32 u; float f; } v; v.u = ((u32)b) << 16; return v.f; }
__device__ __forceinline__ u16 f2bf_rne(float f) {
    u32 x = __float_as_uint(f);
    u32 r = x + 0x7fffu + ((x >> 16) & 1u);
    return (u16)(r >> 16);
}
// truncation split: hi = trunc-bf16(f), lo = rne-bf16(f - hi). total rel err ~2^-17.
__device__ __forceinline__ void split2(float f, u16& hi, u16& lo) {
    u32 bits = __float_as_uint(f);
    hi = (u16)(bits >> 16);
    float resid = f - __uint_as_float(bits & 0xffff0000u);
    lo = (u16)(__float_as_uint(resid) >> 16);
}
__device__ __forceinline__ void split4(float4 f, ushort4& h, ushort4& l) {
    split2(f.x, h.x, l.x); split2(f.y, h.y, l.y);
    split2(f.z, h.z, l.z); split2(f.w, h.w, l.w);
}

// ---- K0: fused prep. blocks [0,1152): rne-quantize aw1/aw2/rw2;
// [1152,1408): transpose+split wq/wk/wv/wout; [1408,1920): KNN + h1 precompute.
__global__ __launch_bounds__(256) void k_preT(const float* __restrict__ aw1,
                                              const float* __restrict__ aw2,
                                              const float* __restrict__ pw2,
                                              const float* __restrict__ wq,
                                              const float* __restrict__ wk,
                                              const float* __restrict__ wv,
                                              const float* __restrict__ wout,
                                              const float* __restrict__ canonical,
                                              const float* __restrict__ pw1,
                                              const float* __restrict__ pb1,
                                              u16* __restrict__ w1hi, u16* __restrict__ w2hi,
                                              u16* __restrict__ rw2hi,
                                              u16* __restrict__ o0h, u16* __restrict__ o0l,
                                              u16* __restrict__ o1h, u16* __restrict__ o1l,
                                              u16* __restrict__ o2h, u16* __restrict__ o2l,
                                              u16* __restrict__ o3h, u16* __restrict__ o3l,
                                              int* __restrict__ nbr,
                                              u16* __restrict__ h1g)
{
    __shared__ float S[64][65];
    const int bx = blockIdx.x, t = threadIdx.x;
    if (bx < 1152) {
        int idx = bx * 256 + t;
        if (idx < 131072) {
            w1hi[idx] = f2bf_rne(aw1[idx]);
        } else if (idx < 262144) {
            int k2 = idx - 131072;
            w2hi[k2] = f2bf_rne(aw2[k2]);
        } else {
            int k2 = idx - 262144;          // k2 = (h*64+d)*64 + p
            int p = k2 & 63; int hd = k2 >> 6;
            int h = hd >> 6; int d = hd & 63;
            rw2hi[k2] = f2bf_rne(pw2[(size_t)p * INNER + h * DH + d]);
        }
        return;
    }
    if (bx < 1408) {
        const int v0 = bx - 1152;           // [0,256)
        const int e0 = (v0 & 7) * 64, c0 = ((v0 >> 3) & 7) * 64, z = v0 >> 6;
        const float* src; u16* dh; u16* dl;
        switch (z) {
            case 0:  src = wq;   dh = o0h; dl = o0l; break;
            case 1:  src = wk;   dh = o1h; dl = o1l; break;
            case 2:  src = wv;   dh = o2h; dl = o2l; break;
            default: src = wout; dh = o3h; dl = o3l; break;
        }
        #pragma unroll
        for (int s = 0; s < 16; ++s) {
            int v = s * 256 + t; int r = v >> 6, c = v & 63;
            S[r][c] = src[(size_t)(e0 + r) * 512 + c0 + c];
        }
        __syncthreads();
        #pragma unroll
        for (int s = 0; s < 16; ++s) {
            int v = s * 256 + t; int c = v >> 6, e = v & 63;
            u16 hi, lo; split2(S[e][c], hi, lo);
            size_t off = (size_t)(c0 + c) * 512 + e0 + e;
            dh[off] = hi; dl[off] = lo;
        }
        return;
    }
    // ---- KNN + h1 (verified body). 512 blocks: b = v>>8, xb = v&255.
    {
        const int v0 = bx - 1408;
        const int b = v0 >> 8, xb = v0 & 255;
        const int l = t & 63, w = t >> 6;
        const int i = xb * 4 + w;
        const float* cb = canonical + (size_t)b * NPT * 3;
        const float qx = cb[i*3+0], qy = cb[i*3+1], qz = cb[i*3+2];
        float d2v[16];
        #pragma unroll
        for (int k = 0; k < 16; ++k) {
            int j = l * 16 + k;
            float dx = __fsub_rn(cb[j*3+0], qx);
            float dy = __fsub_rn(cb[j*3+1], qy);
            float dz = __fsub_rn(cb[j*3+2], qz);
            d2v[k] = __fadd_rn(__fadd_rn(__fmul_rn(dx,dx), __fmul_rn(dy,dy)), __fmul_rn(dz,dz));
        }
        unsigned alive = 0xFFFFu;
        int js[16];
        int* out = nbr + ((size_t)b * NPT + i) * KNN;
        #pragma unroll
        for (int sel = 0; sel < KNN; ++sel) {
            float bv = __builtin_inff(); int bk = 16;
            #pragma unroll
            for (int k = 0; k < 16; ++k) {
                float v = ((alive >> k) & 1u) ? d2v[k] : __builtin_inff();
                if (v < bv) { bv = v; bk = k; }
            }
            int bj = l * 16 + bk;
            #pragma unroll
            for (int m = 32; m >= 1; m >>= 1) {
                float ov = __shfl_xor(bv, m, 64);
                int   oj = __shfl_xor(bj, m, 64);
                if (ov < bv || (ov == bv && oj < bj)) { bv = ov; bj = oj; }
            }
            if (l == 0) out[sel] = bj;
            js[sel] = bj;
            if ((bj >> 4) == l) alive &= ~(1u << (bj & 15));
        }
        const float pw10 = pw1[l], pw11 = pw1[64 + l], pw12 = pw1[128 + l], pb1v = pb1[l];
        u16* hrow = h1g + (((size_t)b * NPT + i) * KNN) * 64 + l;
        #pragma unroll
        for (int j = 0; j < KNN; ++j) {
            int nv = js[j];
            float rx = cb[nv*3+0] - qx;
            float ry = cb[nv*3+1] - qy;
            float rz = cb[nv*3+2] - qz;
            float a = pb1v;
            a = fmaf(rx, pw10, a);
            a = fmaf(ry, pw11, a);
            a = fmaf(rz, pw12, a);
            hrow[j * 64] = f2bf_rne(fmaxf(a, 0.0f));
        }
    }
}

// ---- K1: MFMA projection GEMM (direct staging). D/V stored single-rne bf16.
__global__ __launch_bounds__(256) void k_projM(const float* __restrict__ qf,
                                               const float* __restrict__ kf,
                                               const float* __restrict__ vf,
                                               const u16* __restrict__ wqh, const u16* __restrict__ wql,
                                               const u16* __restrict__ wkh, const u16* __restrict__ wkl,
                                               const u16* __restrict__ wvh, const u16* __restrict__ wvl,
                                               u16* __restrict__ Dws, u16* __restrict__ Vws)
{
    __shared__ u16 S[12][64 * 40];
    const int t = threadIdx.x, l = t & 63, w = t >> 6;
    const int lm = l & 15, lg = (l >> 4) * 8;
    const int g0 = blockIdx.x * 64, c0 = blockIdx.y * 64;
    const int sr = t >> 2, sc = (t & 3) * 8;

    f32x4 accD[4] = {{0,0,0,0},{0,0,0,0},{0,0,0,0},{0,0,0,0}};
    f32x4 accV[4] = {{0,0,0,0},{0,0,0,0},{0,0,0,0},{0,0,0,0}};

    for (int ks = 0; ks < 16; ++ks) {
        const int k0 = ks * 32;
        if (ks) __syncthreads();
        #pragma unroll
        for (int m = 0; m < 3; ++m) {
            const float* sp = (m == 0 ? qf : (m == 1 ? kf : vf))
                              + (size_t)(g0 + sr) * 512 + k0 + sc;
            float4 f0 = *(const float4*)sp;
            float4 f1 = *(const float4*)(sp + 4);
            if (m == 1) {
                f0.x = -f0.x; f0.y = -f0.y; f0.z = -f0.z; f0.w = -f0.w;
                f1.x = -f1.x; f1.y = -f1.y; f1.z = -f1.z; f1.w = -f1.w;
            }
            ushort4 h0, l0, h1, l1;
            split4(f0, h0, l0); split4(f1, h1, l1);
            *(ushort4*)&S[2*m  ][sr * 40 + sc]     = h0;
            *(ushort4*)&S[2*m  ][sr * 40 + sc + 4] = h1;
            *(ushort4*)&S[2*m+1][sr * 40 + sc]     = l0;
            *(ushort4*)&S[2*m+1][sr * 40 + sc + 4] = l1;
        }
        #define STG(p, base) \
            *(uint4*)&S[p][sr * 40 + sc] = *(const uint4*)&(base)[(size_t)(c0 + sr) * 512 + k0 + sc];
        STG(6, wqh) STG(7, wql) STG(8, wkh) STG(9, wkl) STG(10, wvh) STG(11, wvl)
        #undef STG
        __syncthreads();

        const int ao = (w * 16 + lm) * 40 + lg;
        bf16x8 aqh = *(const bf16x8*)&S[0][ao];
        bf16x8 aql = *(const bf16x8*)&S[1][ao];
        bf16x8 akh = *(const bf16x8*)&S[2][ao];
        bf16x8 akl = *(const bf16x8*)&S[3][ao];
        bf16x8 avh = *(const bf16x8*)&S[4][ao];
        bf16x8 avl = *(const bf16x8*)&S[5][ao];
        #pragma unroll
        for (int ct = 0; ct < 4; ++ct) {
            const int bo = (ct * 16 + lm) * 40 + lg;
            bf16x8 bqh = *(const bf16x8*)&S[6][bo];
            bf16x8 bql = *(const bf16x8*)&S[7][bo];
            bf16x8 bkh = *(const bf16x8*)&S[8][bo];
            bf16x8 bkl = *(const bf16x8*)&S[9][bo];
            bf16x8 bvh = *(const bf16x8*)&S[10][bo];
            bf16x8 bvl = *(const bf16x8*)&S[11][bo];
            accD[ct] = __builtin_amdgcn_mfma_f32_16x16x32_bf16(aqh, bqh, accD[ct], 0, 0, 0);
            accD[ct] = __builtin_amdgcn_mfma_f32_16x16x32_bf16(aql, bqh, accD[ct], 0, 0, 0);
            accD[ct] = __builtin_amdgcn_mfma_f32_16x16x32_bf16(aqh, bql, accD[ct], 0, 0, 0);
            accD[ct] = __builtin_amdgcn_mfma_f32_16x16x32_bf16(akh, bkh, accD[ct], 0, 0, 0);
            accD[ct] = __builtin_amdgcn_mfma_f32_16x16x32_bf16(akl, bkh, accD[ct], 0, 0, 0);
            accD[ct] = __builtin_amdgcn_mfma_f32_16x16x32_bf16(akh, bkl, accD[ct], 0, 0, 0);
            accV[ct] = __builtin_amdgcn_mfma_f32_16x16x32_bf16(avh, bvh, accV[ct], 0, 0, 0);
            accV[ct] = __builtin_amdgcn_mfma_f32_16x16x32_bf16(avl, bvh, accV[ct], 0, 0, 0);
            accV[ct] = __builtin_amdgcn_mfma_f32_16x16x32_bf16(avh, bvl, accV[ct], 0, 0, 0);
        }
    }

    const int b = blockIdx.x >> 4;
    const int h = blockIdx.y;
    #pragma unroll
    for (int ct = 0; ct < 4; ++ct) {
        #pragma unroll
        for (int r = 0; r < 4; ++r) {
            int g = g0 + w * 16 + (l >> 4) * 4 + r;
            int i = g & 1023;
            size_t off = (((size_t)(b * HH + h)) * NPT + i) * DH + ct * 16 + lm;
            Dws[off] = f2bf_rne(accD[ct][r]);
            Vws[off] = f2bf_rne(accV[ct][r]);
        }
    }
}

// ---- K3: MFMA attn kernel. 16 i's per block; bf16 D/V gathers; prod fused.
__global__ __launch_bounds__(256, 3) void k_attn(const u16* __restrict__ Dws,
                                              const u16* __restrict__ Vws,
                                              const int* __restrict__ nbr,
                                              const float* __restrict__ pb2,
                                              const float* __restrict__ ab1,
                                              const float* __restrict__ ab2,
                                              const u16* __restrict__ w1hi,
                                              const u16* __restrict__ w2hi,
                                              const u16* __restrict__ rw2hi,
                                              const u16* __restrict__ h1g,
                                              u16* __restrict__ prodb,
                                              float* __restrict__ npart2)
{
    const int it = blockIdx.x, h = blockIdx.y, b = blockIdx.z, t = threadIdx.x;
    const int l = t & 63, w = t >> 6;
    const int lm = l & 15, lg = (l >> 4) * 8;
    const int dd = w * 16 + lm;

    __shared__ u16 Xs[2][16 * 72];
    __shared__ u16 Hs[2][16 * 264];
    __shared__ u16 rw2s[64 * 72];
    __shared__ int nbrrow[2 * KNN];

    bf16x8 w1f[8], w2f[8];
    float b1v[4];
    #pragma unroll
    for (int q = 0; q < 4; ++q) {
        int e = (w * 4 + q) * 16 + lm;
        b1v[q] = ab1[h * AINNER + e];
        #pragma unroll
        for (int kc = 0; kc < 2; ++kc)
            w1f[q*2+kc] = *(const bf16x8*)&w1hi[((size_t)(h * AINNER + e)) * DH + kc * 32 + lg];
    }
    const float b2v  = ab2[h * DH + dd];
    const float pb2v = pb2[h * DH + dd];
    #pragma unroll
    for (int kc = 0; kc < 8; ++kc)
        w2f[kc] = *(const bf16x8*)&w2hi[((size_t)(h * DH + dd)) * AINNER + kc * 32 + lg];

    for (int v = t; v < 64 * 64; v += 256) {
        int d = v >> 6, p = v & 63;
        rw2s[d * 72 + p] = rw2hi[(h * DH + d) * POSH + p];
    }
    if (t < 2 * KNN)
        nbrrow[t] = nbr[((size_t)b * NPT + h * 128 + it * 2 + (t >> 4)) * KNN + (t & 15)];
    __syncthreads();

    float dvp[2][4], vwp[2][4];
    bf16x8 h1f[2][2];
    auto gather = [&](int pp) {
        #pragma unroll
        for (int u = 0; u < 2; ++u) {
            const int ti = 2 * pp + u;                 // [0,16)
            const int i = it * 16 + ti;
            #pragma unroll
            for (int r = 0; r < 4; ++r) {
                int j = (l >> 4) * 4 + r;
                int nv = nbrrow[((ti >> 3) << 4) + 2 * (ti & 7) + (j >> 3)];
                size_t off = (((size_t)b * HH + (nv >> 7)) * NPT + (nv & 127) * 8 + (j & 7)) * DH + dd;
                dvp[u][r] = bf2f(Dws[off]);
                vwp[u][r] = bf2f(Vws[off]);
            }
            const u16* hb = h1g + (((size_t)b * NPT + i) * KNN + lm) * 64;
            h1f[u][0] = *(const bf16x8*)&hb[lg];
            h1f[u][1] = *(const bf16x8*)&hb[32 + lg];
        }
    };
    gather(0);

    float npacc[4] = {0.f, 0.f, 0.f, 0.f};
    float vvreg[2][4];

    for (int p = 0; p < 8; ++p) {
        // ---- Phase B: rpe MFMA (1-pass) + X rne; vv -> regs; prefetch next pair
        #pragma unroll
        for (int u = 0; u < 2; ++u) {
            f32x4 racc = {0.f, 0.f, 0.f, 0.f};
            #pragma unroll
            for (int kc = 0; kc < 2; ++kc) {
                bf16x8 rb = *(const bf16x8*)&rw2s[dd * 72 + kc * 32 + lg];
                racc = __builtin_amdgcn_mfma_f32_16x16x32_bf16(h1f[u][kc], rb, racc, 0, 0, 0);
            }
            #pragma unroll
            for (int r = 0; r < 4; ++r) {
                int j = (l >> 4) * 4 + r;
                float rp = racc[r] + pb2v;
                Xs[u][j * 72 + dd] = f2bf_rne(dvp[u][r] + rp);
                vvreg[u][r] = vwp[u][r] + rp;
            }
        }
        if (p < 7) gather(p + 1);
        __syncthreads();
        // ---- Phase C: MLP1 (1-pass): H = relu(X @ W1^T + b1), single-rne
        #pragma unroll
        for (int u = 0; u < 2; ++u) {
            f32x4 acc1[4] = {{0,0,0,0},{0,0,0,0},{0,0,0,0},{0,0,0,0}};
            #pragma unroll
            for (int kc = 0; kc < 2; ++kc) {
                bf16x8 ah = *(const bf16x8*)&Xs[u][lm * 72 + kc * 32 + lg];
                #pragma unroll
                for (int q = 0; q < 4; ++q)
                    acc1[q] = __builtin_amdgcn_mfma_f32_16x16x32_bf16(ah, w1f[q*2+kc], acc1[q], 0, 0, 0);
            }
            #pragma unroll
            for (int q = 0; q < 4; ++q) {
                int ee = (w * 4 + q) * 16 + lm;
                #pragma unroll
                for (int r = 0; r < 4; ++r) {
                    int jj = (l >> 4) * 4 + r;
                    Hs[u][jj * 264 + ee] = f2bf_rne(fmaxf(acc1[q][r] + b1v[q], 0.0f));
                }
            }
        }
        __syncthreads();
        // ---- Phase D: MLP2 (1-pass) + in-wave softmax + prod store + norm partial
        #pragma unroll
        for (int u = 0; u < 2; ++u) {
            const int i = it * 16 + 2 * p + u;
            f32x4 acc2[4] = {{0,0,0,0},{0,0,0,0},{0,0,0,0},{0,0,0,0}};
            #pragma unroll
            for (int kc = 0; kc < 8; ++kc) {
                bf16x8 ah = *(const bf16x8*)&Hs[u][lm * 264 + kc * 32 + lg];
                acc2[kc & 3] = __builtin_amdgcn_mfma_f32_16x16x32_bf16(ah, w2f[kc], acc2[kc & 3], 0, 0, 0);
            }
            float sim[4];
            #pragma unroll
            for (int r = 0; r < 4; ++r)
                sim[r] = ((acc2[0][r] + acc2[1][r]) + (acc2[2][r] + acc2[3][r])) + b2v;
            float m = fmaxf(fmaxf(sim[0], sim[1]), fmaxf(sim[2], sim[3]));
            m = fmaxf(m, __shfl_xor(m, 16, 64));
            m = fmaxf(m, __shfl_xor(m, 32, 64));
            float ex[4], s = 0.0f;
            #pragma unroll
            for (int r = 0; r < 4; ++r) { ex[r] = __expf(sim[r] - m); s += ex[r]; }
            s += __shfl_xor(s, 16, 64);
            s += __shfl_xor(s, 32, 64);
            float inv = 1.0f / s;
            u16* po = prodb + (((size_t)(b * HH + h) * NPT + i) * KNN) * DH + dd;
            #pragma unroll
            for (int r = 0; r < 4; ++r) {
                float af = ex[r] * inv;                      // f32 attn
                po[((l >> 4) * 4 + r) * DH] = f2bf_rne(af * vvreg[u][r]);
                npacc[r] = fmaf(af, af, npacc[r]);
            }
        }
        // no trailing barrier: Xs/Hs next writes are >=2 barriers past last reads
    }

    float* np = npart2 + ((size_t)((b * HH + h) * 64 + it)) * 1024 + ((l >> 4) * 4) * 64 + dd;
    #pragma unroll
    for (int r = 0; r < 4; ++r) np[r * 64] = npacc[r];
}

// ---- K4: reduce 64 block partials -> nrm = sqrt(sum). 256 blocks, 4-way chunked.
__global__ __launch_bounds__(256) void k_normR(const float* __restrict__ npart2, float* __restrict__ nrm)
{
    __shared__ float red[256];
    const int vout = blockIdx.x * 64 + (threadIdx.x & 63);
    const int chunk = threadIdx.x >> 6;
    const int bh = vout >> 10, jd = vout & 1023;
    const float* src = npart2 + (size_t)bh * 65536 + jd + (size_t)chunk * 16384;
    float s = 0.0f;
    #pragma unroll 4
    for (int k = 0; k < 16; ++k) s += src[k * 1024];
    red[threadIdx.x] = s;
    __syncthreads();
    if (chunk == 0) {
        float tot = (red[threadIdx.x] + red[threadIdx.x + 64])
                  + (red[threadIdx.x + 128] + red[threadIdx.x + 192]);
        nrm[vout] = sqrtf(tot);
    }
}

// ---- K5: agg = sum_j prod[i,j,d] * rn[j,d] — 16 i's per block; bf16 agg out.
__global__ __launch_bounds__(256) void k_agg(const u16* __restrict__ prodb,
                                             const float* __restrict__ nrm,
                                             u16* __restrict__ aggb)
{
    const int it = blockIdx.x, h = blockIdx.y, b = blockIdx.z, t = threadIdx.x;
    const int l = t & 63, w = t >> 6;
    __shared__ float rn[KNN * DH];
    for (int v = t; v < KNN * DH; v += 256)
        rn[v] = 1.0f / fmaxf(nrm[(size_t)(b * HH + h) * 1024 + v], 1e-12f);
    __syncthreads();
    const int dbase = (l & 7) * 8;
    float4 ra = *(const float4*)&rn[(l >> 3) * 64 + dbase];
    float4 rb = *(const float4*)&rn[(l >> 3) * 64 + dbase + 4];
    float4 rc = *(const float4*)&rn[(8 + (l >> 3)) * 64 + dbase];
    float4 rd = *(const float4*)&rn[(8 + (l >> 3)) * 64 + dbase + 4];
    const float r0[8] = {ra.x, ra.y, ra.z, ra.w, rb.x, rb.y, rb.z, rb.w};
    const float r1[8] = {rc.x, rc.y, rc.z, rc.w, rd.x, rd.y, rd.z, rd.w};
    for (int g4 = 0; g4 < 4; ++g4) {
        const int i = it * 16 + g4 * 4 + w;
        const size_t row = ((size_t)(b * HH + h) * NPT + i) * (KNN * DH);
        bf16x8 p0 = *(const bf16x8*)&prodb[row + l * 8];
        bf16x8 p1 = *(const bf16x8*)&prodb[row + 512 + l * 8];
        float acc[8];
        #pragma unroll
        for (int e = 0; e < 8; ++e)
            acc[e] = bf2f((u16)p0[e]) * r0[e] + bf2f((u16)p1[e]) * r1[e];
        #pragma unroll
        for (int mask = 8; mask <= 32; mask <<= 1)
            #pragma unroll
            for (int e = 0; e < 8; ++e)
                acc[e] += __shfl_xor(acc[e], mask, 64);
        if (l < 8) {
            size_t off = ((size_t)b * NPT + i) * INNER + h * DH + l * 8;
            ushort4 a0, a1;
            a0.x = f2bf_rne(acc[0]); a0.y = f2bf_rne(acc[1]);
            a0.z = f2bf_rne(acc[2]); a0.w = f2bf_rne(acc[3]);
            a1.x = f2bf_rne(acc[4]); a1.y = f2bf_rne(acc[5]);
            a1.z = f2bf_rne(acc[6]); a1.w = f2bf_rne(acc[7]);
            *(ushort4*)&aggb[off]     = a0;
            *(ushort4*)&aggb[off + 4] = a1;
        }
    }
}

// ---- K6: MFMA out GEMM: out = agg(bf16) @ (wth+wtl) + b_out, 2-pass.
__global__ __launch_bounds__(256) void k_outM(const u16* __restrict__ aggb,
                                              const u16* __restrict__ wth, const u16* __restrict__ wtl,
                                              const float* __restrict__ bout,
                                              float* __restrict__ outp)
{
    __shared__ u16 S[3][64 * 40];
    const int t = threadIdx.x, l = t & 63, w = t >> 6;
    const int lm = l & 15, lg = (l >> 4) * 8;
    const int g0 = blockIdx.x * 64, c0 = blockIdx.y * 64;
    const int sr = t >> 2, sc = (t & 3) * 8;

    f32x4 acc[4] = {{0,0,0,0},{0,0,0,0},{0,0,0,0},{0,0,0,0}};
    float bv4[4];
    #pragma unroll
    for (int ct = 0; ct < 4; ++ct) bv4[ct] = bout[c0 + ct * 16 + lm];

    for (int ks = 0; ks < 16; ++ks) {
        const int k0 = ks * 32;
        if (ks) __syncthreads();
        *(uint4*)&S[0][sr * 40 + sc] = *(const uint4*)&aggb[(size_t)(g0 + sr) * 512 + k0 + sc];
        *(uint4*)&S[1][sr * 40 + sc] = *(const uint4*)&wth[(size_t)(c0 + sr) * 512 + k0 + sc];
        *(uint4*)&S[2][sr * 40 + sc] = *(const uint4*)&wtl[(size_t)(c0 + sr) * 512 + k0 + sc];
        __syncthreads();

        const int ao = (w * 16 + lm) * 40 + lg;
        bf16x8 ah = *(const bf16x8*)&S[0][ao];
        #pragma unroll
        for (int ct = 0; ct < 4; ++ct) {
            const int bo = (ct * 16 + lm) * 40 + lg;
            bf16x8 bh = *(const bf16x8*)&S[1][bo];
            bf16x8 bl = *(const bf16x8*)&S[2][bo];
            acc[ct] = __builtin_amdgcn_mfma_f32_16x16x32_bf16(ah, bh, acc[ct], 0, 0, 0);
            acc[ct] = __builtin_amdgcn_mfma_f32_16x16x32_bf16(ah, bl, acc[ct], 0, 0, 0);
        }
    }
    #pragma unroll
    for (int ct = 0; ct < 4; ++ct) {
        #pragma unroll
        for (int r = 0; r < 4; ++r) {
            int g = g0 + w * 16 + (l >> 4) * 4 + r;
            outp[(size_t)g * 512 + c0 + ct * 16 + lm] = acc[ct][r] + bv4[ct];
        }
    }
}

extern "C" void kernel_launch(void* const* d_in, const int* in_sizes, int n_in,
                              void* d_out, int out_size, void* d_ws, size_t ws_size,
                              hipStream_t stream) {
    const float* query     = (const float*)d_in[0];
    const float* key_in    = (const float*)d_in[1];
    const float* value     = (const float*)d_in[2];
    const float* canonical = (const float*)d_in[3];
    const float* wq   = (const float*)d_in[4];
    const float* wk   = (const float*)d_in[5];
    const float* wv   = (const float*)d_in[6];
    const float* wout = (const float*)d_in[7];
    const float* bout = (const float*)d_in[8];
    const float* pw1  = (const float*)d_in[9];
    const float* pb1  = (const float*)d_in[10];
    const float* pw2  = (const float*)d_in[11];
    const float* pb2  = (const float*)d_in[12];
    const float* aw1  = (const float*)d_in[13];
    const float* ab1  = (const float*)d_in[14];
    const float* aw2  = (const float*)d_in[15];
    const float* ab2  = (const float*)d_in[16];

    float* ws    = (float*)d_ws;
    u16*   Dws   = (u16*)ws;              // 1,048,576 u16 (in 1M-float slot)
    u16*   Vws   = (u16*)(ws + 1048576);  // 1,048,576 u16
    float* aggp  = ws + 2097152;          // slot reused: aggb single plane
    float* nrm   = ws + 3162112;          // 16,384 f used
    int*   nbr   = (int*)(ws + 3293184);  // 32,768 i32
    float* attnR = ws + 3325952;          // 16,777,216 f region

    u16* aggb = (u16*)aggp;               // 1,048,576 u16

    // region layout: [prodb bf16: 8.39M f][wT planes][free][npart2][h1g]
    u16* prodb = (u16*)attnR;
    u16* pl   = (u16*)(attnR + 8388608);
    u16* wqTh = pl;                u16* wqTl = pl + 262144;
    u16* wkTh = pl + 524288;       u16* wkTl = pl + 786432;
    u16* wvTh = pl + 1048576;      u16* wvTl = pl + 1310720;
    float* npart2 = attnR + 12582912;     // 1,048,576 f used
    u16* h1g = (u16*)(attnR + 14680064);  // 2,097,152 u16

    u16* u16b  = (u16*)(ws + 20103168);
    u16* w1hi  = u16b;                    // 131,072 u16
    u16* w2hi  = u16b + 262144;           // 131,072 u16
    u16* rw2hi = u16b + 524288;           // 32,768 u16
    u16* wouTh = u16b + 17367040;
    u16* wouTl = u16b + 17629184;         // end ~116 MB total ws

    k_preT<<<1920, 256, 0, stream>>>(aw1, aw2, pw2, wq, wk, wv, wout,
                                     canonical, pw1, pb1,
                                     w1hi, w2hi, rw2hi,
                                     wqTh, wqTl, wkTh, wkTl, wvTh, wvTl, wouTh, wouTl,
                                     nbr, h1g);
    k_projM<<<dim3(32, 8), 256, 0, stream>>>(query, key_in, value,
                                             wqTh, wqTl, wkTh, wkTl, wvTh, wvTl, Dws, Vws);
    k_attn<<<dim3(64, HH, BS), 256, 0, stream>>>(Dws, Vws, nbr, pb2, ab1, ab2,
                                                 w1hi, w2hi, rw2hi, h1g, prodb, npart2);
    k_normR<<<256, 256, 0, stream>>>(npart2, nrm);
    k_agg<<<dim3(64, HH, BS), 256, 0, stream>>>(prodb, nrm, aggb);
    k_outM<<<dim3(32, 8), 256, 0, stream>>>(aggb, wouTh, wouTl, bout, (float*)d_out);
}

// Round 17
// 137.992 us; speedup vs baseline: 1.1245x; 1.1245x over previous
//
#include <hip/hip_runtime.h>

// MultiHeadVectorAttention — round 17: revert D/V to f32 (bf16 scattered gathers
// were latency-regressive: r16 k_attn 59->76us); keep agg-bf16 + 2-pass outM.
// bs=2, n=1024, H=8, DH=64, K=16, EMB=INNER=512, AINNER=256, POSH=64.

#define BS 2
#define NPT 1024
#define HH 8
#define DH 64
#define KNN 16
#define EMB 512
#define INNER 512
#define AINNER 256
#define POSH 64

typedef unsigned short u16;
typedef unsigned int u32;
typedef __attribute__((ext_vector_type(8))) short bf16x8;
typedef __attribute__((ext_vector_type(4))) float f32x4;

__device__ __forceinline__ float bf2f(u16 b) { union { u32 u; float f; } v; v.u = ((u32)b) << 16; return v.f; }
__device__ __forceinline__ u16 f2bf_rne(float f) {
    u32 x = __float_as_uint(f);
    u32 r = x + 0x7fffu + ((x >> 16) & 1u);
    return (u16)(r >> 16);
}
// truncation split: hi = trunc-bf16(f), lo = rne-bf16(f - hi). total rel err ~2^-17.
__device__ __forceinline__ void split2(float f, u16& hi, u16& lo) {
    u32 bits = __float_as_uint(f);
    hi = (u16)(bits >> 16);
    float resid = f - __uint_as_float(bits & 0xffff0000u);
    lo = (u16)(__float_as_uint(resid) >> 16);
}
__device__ __forceinline__ void split4(float4 f, ushort4& h, ushort4& l) {
    split2(f.x, h.x, l.x); split2(f.y, h.y, l.y);
    split2(f.z, h.z, l.z); split2(f.w, h.w, l.w);
}

// ---- K0: fused prep. blocks [0,1152): rne-quantize aw1/aw2/rw2;
// [1152,1408): transpose+split wq/wk/wv/wout; [1408,1920): KNN + h1 precompute.
__global__ __launch_bounds__(256) void k_preT(const float* __restrict__ aw1,
                                              const float* __restrict__ aw2,
                                              const float* __restrict__ pw2,
                                              const float* __restrict__ wq,
                                              const float* __restrict__ wk,
                                              const float* __restrict__ wv,
                                              const float* __restrict__ wout,
                                              const float* __restrict__ canonical,
                                              const float* __restrict__ pw1,
                                              const float* __restrict__ pb1,
                                              u16* __restrict__ w1hi, u16* __restrict__ w2hi,
                                              u16* __restrict__ rw2hi,
                                              u16* __restrict__ o0h, u16* __restrict__ o0l,
                                              u16* __restrict__ o1h, u16* __restrict__ o1l,
                                              u16* __restrict__ o2h, u16* __restrict__ o2l,
                                              u16* __restrict__ o3h, u16* __restrict__ o3l,
                                              int* __restrict__ nbr,
                                              u16* __restrict__ h1g)
{
    __shared__ float S[64][65];
    const int bx = blockIdx.x, t = threadIdx.x;
    if (bx < 1152) {
        int idx = bx * 256 + t;
        if (idx < 131072) {
            w1hi[idx] = f2bf_rne(aw1[idx]);
        } else if (idx < 262144) {
            int k2 = idx - 131072;
            w2hi[k2] = f2bf_rne(aw2[k2]);
        } else {
            int k2 = idx - 262144;          // k2 = (h*64+d)*64 + p
            int p = k2 & 63; int hd = k2 >> 6;
            int h = hd >> 6; int d = hd & 63;
            rw2hi[k2] = f2bf_rne(pw2[(size_t)p * INNER + h * DH + d]);
        }
        return;
    }
    if (bx < 1408) {
        const int v0 = bx - 1152;           // [0,256)
        const int e0 = (v0 & 7) * 64, c0 = ((v0 >> 3) & 7) * 64, z = v0 >> 6;
        const float* src; u16* dh; u16* dl;
        switch (z) {
            case 0:  src = wq;   dh = o0h; dl = o0l; break;
            case 1:  src = wk;   dh = o1h; dl = o1l; break;
            case 2:  src = wv;   dh = o2h; dl = o2l; break;
            default: src = wout; dh = o3h; dl = o3l; break;
        }
        #pragma unroll
        for (int s = 0; s < 16; ++s) {
            int v = s * 256 + t; int r = v >> 6, c = v & 63;
            S[r][c] = src[(size_t)(e0 + r) * 512 + c0 + c];
        }
        __syncthreads();
        #pragma unroll
        for (int s = 0; s < 16; ++s) {
            int v = s * 256 + t; int c = v >> 6, e = v & 63;
            u16 hi, lo; split2(S[e][c], hi, lo);
            size_t off = (size_t)(c0 + c) * 512 + e0 + e;
            dh[off] = hi; dl[off] = lo;
        }
        return;
    }
    // ---- KNN + h1 (verified body). 512 blocks: b = v>>8, xb = v&255.
    {
        const int v0 = bx - 1408;
        const int b = v0 >> 8, xb = v0 & 255;
        const int l = t & 63, w = t >> 6;
        const int i = xb * 4 + w;
        const float* cb = canonical + (size_t)b * NPT * 3;
        const float qx = cb[i*3+0], qy = cb[i*3+1], qz = cb[i*3+2];
        float d2v[16];
        #pragma unroll
        for (int k = 0; k < 16; ++k) {
            int j = l * 16 + k;
            float dx = __fsub_rn(cb[j*3+0], qx);
            float dy = __fsub_rn(cb[j*3+1], qy);
            float dz = __fsub_rn(cb[j*3+2], qz);
            d2v[k] = __fadd_rn(__fadd_rn(__fmul_rn(dx,dx), __fmul_rn(dy,dy)), __fmul_rn(dz,dz));
        }
        unsigned alive = 0xFFFFu;
        int js[16];
        int* out = nbr + ((size_t)b * NPT + i) * KNN;
        #pragma unroll
        for (int sel = 0; sel < KNN; ++sel) {
            float bv = __builtin_inff(); int bk = 16;
            #pragma unroll
            for (int k = 0; k < 16; ++k) {
                float v = ((alive >> k) & 1u) ? d2v[k] : __builtin_inff();
                if (v < bv) { bv = v; bk = k; }
            }
            int bj = l * 16 + bk;
            #pragma unroll
            for (int m = 32; m >= 1; m >>= 1) {
                float ov = __shfl_xor(bv, m, 64);
                int   oj = __shfl_xor(bj, m, 64);
                if (ov < bv || (ov == bv && oj < bj)) { bv = ov; bj = oj; }
            }
            if (l == 0) out[sel] = bj;
            js[sel] = bj;
            if ((bj >> 4) == l) alive &= ~(1u << (bj & 15));
        }
        const float pw10 = pw1[l], pw11 = pw1[64 + l], pw12 = pw1[128 + l], pb1v = pb1[l];
        u16* hrow = h1g + (((size_t)b * NPT + i) * KNN) * 64 + l;
        #pragma unroll
        for (int j = 0; j < KNN; ++j) {
            int nv = js[j];
            float rx = cb[nv*3+0] - qx;
            float ry = cb[nv*3+1] - qy;
            float rz = cb[nv*3+2] - qz;
            float a = pb1v;
            a = fmaf(rx, pw10, a);
            a = fmaf(ry, pw11, a);
            a = fmaf(rz, pw12, a);
            hrow[j * 64] = f2bf_rne(fmaxf(a, 0.0f));
        }
    }
}

// ---- K1: MFMA projection GEMM (round-15 verified: f32 D/V outputs).
__global__ __launch_bounds__(256) void k_projM(const float* __restrict__ qf,
                                               const float* __restrict__ kf,
                                               const float* __restrict__ vf,
                                               const u16* __restrict__ wqh, const u16* __restrict__ wql,
                                               const u16* __restrict__ wkh, const u16* __restrict__ wkl,
                                               const u16* __restrict__ wvh, const u16* __restrict__ wvl,
                                               float* __restrict__ Dws, float* __restrict__ Vws)
{
    __shared__ u16 S[12][64 * 40];
    const int t = threadIdx.x, l = t & 63, w = t >> 6;
    const int lm = l & 15, lg = (l >> 4) * 8;
    const int g0 = blockIdx.x * 64, c0 = blockIdx.y * 64;
    const int sr = t >> 2, sc = (t & 3) * 8;

    f32x4 accD[4] = {{0,0,0,0},{0,0,0,0},{0,0,0,0},{0,0,0,0}};
    f32x4 accV[4] = {{0,0,0,0},{0,0,0,0},{0,0,0,0},{0,0,0,0}};

    for (int ks = 0; ks < 16; ++ks) {
        const int k0 = ks * 32;
        if (ks) __syncthreads();
        #pragma unroll
        for (int m = 0; m < 3; ++m) {
            const float* sp = (m == 0 ? qf : (m == 1 ? kf : vf))
                              + (size_t)(g0 + sr) * 512 + k0 + sc;
            float4 f0 = *(const float4*)sp;
            float4 f1 = *(const float4*)(sp + 4);
            if (m == 1) {
                f0.x = -f0.x; f0.y = -f0.y; f0.z = -f0.z; f0.w = -f0.w;
                f1.x = -f1.x; f1.y = -f1.y; f1.z = -f1.z; f1.w = -f1.w;
            }
            ushort4 h0, l0, h1, l1;
            split4(f0, h0, l0); split4(f1, h1, l1);
            *(ushort4*)&S[2*m  ][sr * 40 + sc]     = h0;
            *(ushort4*)&S[2*m  ][sr * 40 + sc + 4] = h1;
            *(ushort4*)&S[2*m+1][sr * 40 + sc]     = l0;
            *(ushort4*)&S[2*m+1][sr * 40 + sc + 4] = l1;
        }
        #define STG(p, base) \
            *(uint4*)&S[p][sr * 40 + sc] = *(const uint4*)&(base)[(size_t)(c0 + sr) * 512 + k0 + sc];
        STG(6, wqh) STG(7, wql) STG(8, wkh) STG(9, wkl) STG(10, wvh) STG(11, wvl)
        #undef STG
        __syncthreads();

        const int ao = (w * 16 + lm) * 40 + lg;
        bf16x8 aqh = *(const bf16x8*)&S[0][ao];
        bf16x8 aql = *(const bf16x8*)&S[1][ao];
        bf16x8 akh = *(const bf16x8*)&S[2][ao];
        bf16x8 akl = *(const bf16x8*)&S[3][ao];
        bf16x8 avh = *(const bf16x8*)&S[4][ao];
        bf16x8 avl = *(const bf16x8*)&S[5][ao];
        #pragma unroll
        for (int ct = 0; ct < 4; ++ct) {
            const int bo = (ct * 16 + lm) * 40 + lg;
            bf16x8 bqh = *(const bf16x8*)&S[6][bo];
            bf16x8 bql = *(const bf16x8*)&S[7][bo];
            bf16x8 bkh = *(const bf16x8*)&S[8][bo];
            bf16x8 bkl = *(const bf16x8*)&S[9][bo];
            bf16x8 bvh = *(const bf16x8*)&S[10][bo];
            bf16x8 bvl = *(const bf16x8*)&S[11][bo];
            accD[ct] = __builtin_amdgcn_mfma_f32_16x16x32_bf16(aqh, bqh, accD[ct], 0, 0, 0);
            accD[ct] = __builtin_amdgcn_mfma_f32_16x16x32_bf16(aql, bqh, accD[ct], 0, 0, 0);
            accD[ct] = __builtin_amdgcn_mfma_f32_16x16x32_bf16(aqh, bql, accD[ct], 0, 0, 0);
            accD[ct] = __builtin_amdgcn_mfma_f32_16x16x32_bf16(akh, bkh, accD[ct], 0, 0, 0);
            accD[ct] = __builtin_amdgcn_mfma_f32_16x16x32_bf16(akl, bkh, accD[ct], 0, 0, 0);
            accD[ct] = __builtin_amdgcn_mfma_f32_16x16x32_bf16(akh, bkl, accD[ct], 0, 0, 0);
            accV[ct] = __builtin_amdgcn_mfma_f32_16x16x32_bf16(avh, bvh, accV[ct], 0, 0, 0);
            accV[ct] = __builtin_amdgcn_mfma_f32_16x16x32_bf16(avl, bvh, accV[ct], 0, 0, 0);
            accV[ct] = __builtin_amdgcn_mfma_f32_16x16x32_bf16(avh, bvl, accV[ct], 0, 0, 0);
        }
    }

    const int b = blockIdx.x >> 4;
    const int h = blockIdx.y;
    #pragma unroll
    for (int ct = 0; ct < 4; ++ct) {
        #pragma unroll
        for (int r = 0; r < 4; ++r) {
            int g = g0 + w * 16 + (l >> 4) * 4 + r;
            int i = g & 1023;
            size_t off = (((size_t)(b * HH + h)) * NPT + i) * DH + ct * 16 + lm;
            Dws[off] = accD[ct][r];
            Vws[off] = accV[ct][r];
        }
    }
}

// ---- K3: MFMA attn kernel (round-15 verified: f32 D/V gathers). prod fused.
__global__ __launch_bounds__(256, 3) void k_attn(const float* __restrict__ Dws,
                                              const float* __restrict__ Vws,
                                              const int* __restrict__ nbr,
                                              const float* __restrict__ pb2,
                                              const float* __restrict__ ab1,
                                              const float* __restrict__ ab2,
                                              const u16* __restrict__ w1hi,
                                              const u16* __restrict__ w2hi,
                                              const u16* __restrict__ rw2hi,
                                              const u16* __restrict__ h1g,
                                              u16* __restrict__ prodb,
                                              float* __restrict__ npart2)
{
    const int it = blockIdx.x, h = blockIdx.y, b = blockIdx.z, t = threadIdx.x;
    const int l = t & 63, w = t >> 6;
    const int lm = l & 15, lg = (l >> 4) * 8;
    const int dd = w * 16 + lm;

    __shared__ u16 Xs[2][16 * 72];
    __shared__ u16 Hs[2][16 * 264];
    __shared__ u16 rw2s[64 * 72];
    __shared__ int nbrrow[2 * KNN];

    bf16x8 w1f[8], w2f[8];
    float b1v[4];
    #pragma unroll
    for (int q = 0; q < 4; ++q) {
        int e = (w * 4 + q) * 16 + lm;
        b1v[q] = ab1[h * AINNER + e];
        #pragma unroll
        for (int kc = 0; kc < 2; ++kc)
            w1f[q*2+kc] = *(const bf16x8*)&w1hi[((size_t)(h * AINNER + e)) * DH + kc * 32 + lg];
    }
    const float b2v  = ab2[h * DH + dd];
    const float pb2v = pb2[h * DH + dd];
    #pragma unroll
    for (int kc = 0; kc < 8; ++kc)
        w2f[kc] = *(const bf16x8*)&w2hi[((size_t)(h * DH + dd)) * AINNER + kc * 32 + lg];

    for (int v = t; v < 64 * 64; v += 256) {
        int d = v >> 6, p = v & 63;
        rw2s[d * 72 + p] = rw2hi[(h * DH + d) * POSH + p];
    }
    if (t < 2 * KNN)
        nbrrow[t] = nbr[((size_t)b * NPT + h * 128 + it * 2 + (t >> 4)) * KNN + (t & 15)];
    __syncthreads();

    float dvp[2][4], vwp[2][4];
    bf16x8 h1f[2][2];
    auto gather = [&](int pp) {
        #pragma unroll
        for (int u = 0; u < 2; ++u) {
            const int ti = 2 * pp + u;                 // [0,16)
            const int i = it * 16 + ti;
            #pragma unroll
            for (int r = 0; r < 4; ++r) {
                int j = (l >> 4) * 4 + r;
                int nv = nbrrow[((ti >> 3) << 4) + 2 * (ti & 7) + (j >> 3)];
                size_t off = (((size_t)b * HH + (nv >> 7)) * NPT + (nv & 127) * 8 + (j & 7)) * DH + dd;
                dvp[u][r] = Dws[off];
                vwp[u][r] = Vws[off];
            }
            const u16* hb = h1g + (((size_t)b * NPT + i) * KNN + lm) * 64;
            h1f[u][0] = *(const bf16x8*)&hb[lg];
            h1f[u][1] = *(const bf16x8*)&hb[32 + lg];
        }
    };
    gather(0);

    float npacc[4] = {0.f, 0.f, 0.f, 0.f};
    float vvreg[2][4];

    for (int p = 0; p < 8; ++p) {
        // ---- Phase B: rpe MFMA (1-pass) + X rne; vv -> regs; prefetch next pair
        #pragma unroll
        for (int u = 0; u < 2; ++u) {
            f32x4 racc = {0.f, 0.f, 0.f, 0.f};
            #pragma unroll
            for (int kc = 0; kc < 2; ++kc) {
                bf16x8 rb = *(const bf16x8*)&rw2s[dd * 72 + kc * 32 + lg];
                racc = __builtin_amdgcn_mfma_f32_16x16x32_bf16(h1f[u][kc], rb, racc, 0, 0, 0);
            }
            #pragma unroll
            for (int r = 0; r < 4; ++r) {
                int j = (l >> 4) * 4 + r;
                float rp = racc[r] + pb2v;
                Xs[u][j * 72 + dd] = f2bf_rne(dvp[u][r] + rp);
                vvreg[u][r] = vwp[u][r] + rp;
            }
        }
        if (p < 7) gather(p + 1);
        __syncthreads();
        // ---- Phase C: MLP1 (1-pass): H = relu(X @ W1^T + b1), single-rne
        #pragma unroll
        for (int u = 0; u < 2; ++u) {
            f32x4 acc1[4] = {{0,0,0,0},{0,0,0,0},{0,0,0,0},{0,0,0,0}};
            #pragma unroll
            for (int kc = 0; kc < 2; ++kc) {
                bf16x8 ah = *(const bf16x8*)&Xs[u][lm * 72 + kc * 32 + lg];
                #pragma unroll
                for (int q = 0; q < 4; ++q)
                    acc1[q] = __builtin_amdgcn_mfma_f32_16x16x32_bf16(ah, w1f[q*2+kc], acc1[q], 0, 0, 0);
            }
            #pragma unroll
            for (int q = 0; q < 4; ++q) {
                int ee = (w * 4 + q) * 16 + lm;
                #pragma unroll
                for (int r = 0; r < 4; ++r) {
                    int jj = (l >> 4) * 4 + r;
                    Hs[u][jj * 264 + ee] = f2bf_rne(fmaxf(acc1[q][r] + b1v[q], 0.0f));
                }
            }
        }
        __syncthreads();
        // ---- Phase D: MLP2 (1-pass) + in-wave softmax + prod store + norm partial
        #pragma unroll
        for (int u = 0; u < 2; ++u) {
            const int i = it * 16 + 2 * p + u;
            f32x4 acc2[4] = {{0,0,0,0},{0,0,0,0},{0,0,0,0},{0,0,0,0}};
            #pragma unroll
            for (int kc = 0; kc < 8; ++kc) {
                bf16x8 ah = *(const bf16x8*)&Hs[u][lm * 264 + kc * 32 + lg];
                acc2[kc & 3] = __builtin_amdgcn_mfma_f32_16x16x32_bf16(ah, w2f[kc], acc2[kc & 3], 0, 0, 0);
            }
            float sim[4];
            #pragma unroll
            for (int r = 0; r < 4; ++r)
                sim[r] = ((acc2[0][r] + acc2[1][r]) + (acc2[2][r] + acc2[3][r])) + b2v;
            float m = fmaxf(fmaxf(sim[0], sim[1]), fmaxf(sim[2], sim[3]));
            m = fmaxf(m, __shfl_xor(m, 16, 64));
            m = fmaxf(m, __shfl_xor(m, 32, 64));
            float ex[4], s = 0.0f;
            #pragma unroll
            for (int r = 0; r < 4; ++r) { ex[r] = __expf(sim[r] - m); s += ex[r]; }
            s += __shfl_xor(s, 16, 64);
            s += __shfl_xor(s, 32, 64);
            float inv = 1.0f / s;
            u16* po = prodb + (((size_t)(b * HH + h) * NPT + i) * KNN) * DH + dd;
            #pragma unroll
            for (int r = 0; r < 4; ++r) {
                float af = ex[r] * inv;                      // f32 attn
                po[((l >> 4) * 4 + r) * DH] = f2bf_rne(af * vvreg[u][r]);
                npacc[r] = fmaf(af, af, npacc[r]);
            }
        }
        // no trailing barrier: Xs/Hs next writes are >=2 barriers past last reads
    }

    float* np = npart2 + ((size_t)((b * HH + h) * 64 + it)) * 1024 + ((l >> 4) * 4) * 64 + dd;
    #pragma unroll
    for (int r = 0; r < 4; ++r) np[r * 64] = npacc[r];
}

// ---- K4: reduce 64 block partials -> nrm = sqrt(sum). 256 blocks, 4-way chunked.
__global__ __launch_bounds__(256) void k_normR(const float* __restrict__ npart2, float* __restrict__ nrm)
{
    __shared__ float red[256];
    const int vout = blockIdx.x * 64 + (threadIdx.x & 63);
    const int chunk = threadIdx.x >> 6;
    const int bh = vout >> 10, jd = vout & 1023;
    const float* src = npart2 + (size_t)bh * 65536 + jd + (size_t)chunk * 16384;
    float s = 0.0f;
    #pragma unroll 4
    for (int k = 0; k < 16; ++k) s += src[k * 1024];
    red[threadIdx.x] = s;
    __syncthreads();
    if (chunk == 0) {
        float tot = (red[threadIdx.x] + red[threadIdx.x + 64])
                  + (red[threadIdx.x + 128] + red[threadIdx.x + 192]);
        nrm[vout] = sqrtf(tot);
    }
}

// ---- K5: agg = sum_j prod[i,j,d] * rn[j,d] — 16 i's per block; bf16 agg out.
__global__ __launch_bounds__(256) void k_agg(const u16* __restrict__ prodb,
                                             const float* __restrict__ nrm,
                                             u16* __restrict__ aggb)
{
    const int it = blockIdx.x, h = blockIdx.y, b = blockIdx.z, t = threadIdx.x;
    const int l = t & 63, w = t >> 6;
    __shared__ float rn[KNN * DH];
    for (int v = t; v < KNN * DH; v += 256)
        rn[v] = 1.0f / fmaxf(nrm[(size_t)(b * HH + h) * 1024 + v], 1e-12f);
    __syncthreads();
    const int dbase = (l & 7) * 8;
    float4 ra = *(const float4*)&rn[(l >> 3) * 64 + dbase];
    float4 rb = *(const float4*)&rn[(l >> 3) * 64 + dbase + 4];
    float4 rc = *(const float4*)&rn[(8 + (l >> 3)) * 64 + dbase];
    float4 rd = *(const float4*)&rn[(8 + (l >> 3)) * 64 + dbase + 4];
    const float r0[8] = {ra.x, ra.y, ra.z, ra.w, rb.x, rb.y, rb.z, rb.w};
    const float r1[8] = {rc.x, rc.y, rc.z, rc.w, rd.x, rd.y, rd.z, rd.w};
    for (int g4 = 0; g4 < 4; ++g4) {
        const int i = it * 16 + g4 * 4 + w;
        const size_t row = ((size_t)(b * HH + h) * NPT + i) * (KNN * DH);
        bf16x8 p0 = *(const bf16x8*)&prodb[row + l * 8];
        bf16x8 p1 = *(const bf16x8*)&prodb[row + 512 + l * 8];
        float acc[8];
        #pragma unroll
        for (int e = 0; e < 8; ++e)
            acc[e] = bf2f((u16)p0[e]) * r0[e] + bf2f((u16)p1[e]) * r1[e];
        #pragma unroll
        for (int mask = 8; mask <= 32; mask <<= 1)
            #pragma unroll
            for (int e = 0; e < 8; ++e)
                acc[e] += __shfl_xor(acc[e], mask, 64);
        if (l < 8) {
            size_t off = ((size_t)b * NPT + i) * INNER + h * DH + l * 8;
            ushort4 a0, a1;
            a0.x = f2bf_rne(acc[0]); a0.y = f2bf_rne(acc[1]);
            a0.z = f2bf_rne(acc[2]); a0.w = f2bf_rne(acc[3]);
            a1.x = f2bf_rne(acc[4]); a1.y = f2bf_rne(acc[5]);
            a1.z = f2bf_rne(acc[6]); a1.w = f2bf_rne(acc[7]);
            *(ushort4*)&aggb[off]     = a0;
            *(ushort4*)&aggb[off + 4] = a1;
        }
    }
}

// ---- K6: MFMA out GEMM: out = agg(bf16) @ (wth+wtl) + b_out, 2-pass.
__global__ __launch_bounds__(256) void k_outM(const u16* __restrict__ aggb,
                                              const u16* __restrict__ wth, const u16* __restrict__ wtl,
                                              const float* __restrict__ bout,
                                              float* __restrict__ outp)
{
    __shared__ u16 S[3][64 * 40];
    const int t = threadIdx.x, l = t & 63, w = t >> 6;
    const int lm = l & 15, lg = (l >> 4) * 8;
    const int g0 = blockIdx.x * 64, c0 = blockIdx.y * 64;
    const int sr = t >> 2, sc = (t & 3) * 8;

    f32x4 acc[4] = {{0,0,0,0},{0,0,0,0},{0,0,0,0},{0,0,0,0}};
    float bv4[4];
    #pragma unroll
    for (int ct = 0; ct < 4; ++ct) bv4[ct] = bout[c0 + ct * 16 + lm];

    for (int ks = 0; ks < 16; ++ks) {
        const int k0 = ks * 32;
        if (ks) __syncthreads();
        *(uint4*)&S[0][sr * 40 + sc] = *(const uint4*)&aggb[(size_t)(g0 + sr) * 512 + k0 + sc];
        *(uint4*)&S[1][sr * 40 + sc] = *(const uint4*)&wth[(size_t)(c0 + sr) * 512 + k0 + sc];
        *(uint4*)&S[2][sr * 40 + sc] = *(const uint4*)&wtl[(size_t)(c0 + sr) * 512 + k0 + sc];
        __syncthreads();

        const int ao = (w * 16 + lm) * 40 + lg;
        bf16x8 ah = *(const bf16x8*)&S[0][ao];
        #pragma unroll
        for (int ct = 0; ct < 4; ++ct) {
            const int bo = (ct * 16 + lm) * 40 + lg;
            bf16x8 bh = *(const bf16x8*)&S[1][bo];
            bf16x8 bl = *(const bf16x8*)&S[2][bo];
            acc[ct] = __builtin_amdgcn_mfma_f32_16x16x32_bf16(ah, bh, acc[ct], 0, 0, 0);
            acc[ct] = __builtin_amdgcn_mfma_f32_16x16x32_bf16(ah, bl, acc[ct], 0, 0, 0);
        }
    }
    #pragma unroll
    for (int ct = 0; ct < 4; ++ct) {
        #pragma unroll
        for (int r = 0; r < 4; ++r) {
            int g = g0 + w * 16 + (l >> 4) * 4 + r;
            outp[(size_t)g * 512 + c0 + ct * 16 + lm] = acc[ct][r] + bv4[ct];
        }
    }
}

extern "C" void kernel_launch(void* const* d_in, const int* in_sizes, int n_in,
                              void* d_out, int out_size, void* d_ws, size_t ws_size,
                              hipStream_t stream) {
    const float* query     = (const float*)d_in[0];
    const float* key_in    = (const float*)d_in[1];
    const float* value     = (const float*)d_in[2];
    const float* canonical = (const float*)d_in[3];
    const float* wq   = (const float*)d_in[4];
    const float* wk   = (const float*)d_in[5];
    const float* wv   = (const float*)d_in[6];
    const float* wout = (const float*)d_in[7];
    const float* bout = (const float*)d_in[8];
    const float* pw1  = (const float*)d_in[9];
    const float* pb1  = (const float*)d_in[10];
    const float* pw2  = (const float*)d_in[11];
    const float* pb2  = (const float*)d_in[12];
    const float* aw1  = (const float*)d_in[13];
    const float* ab1  = (const float*)d_in[14];
    const float* aw2  = (const float*)d_in[15];
    const float* ab2  = (const float*)d_in[16];

    float* ws    = (float*)d_ws;
    float* Dws   = ws;                    // 1,048,576 f
    float* Vws   = ws + 1048576;          // 1,048,576 f
    float* aggp  = ws + 2097152;          // aggb single bf16 plane
    float* nrm   = ws + 3162112;          // 16,384 f used
    int*   nbr   = (int*)(ws + 3293184);  // 32,768 i32
    float* attnR = ws + 3325952;          // 16,777,216 f region

    u16* aggb = (u16*)aggp;               // 1,048,576 u16

    // region layout: [prodb bf16: 8.39M f][wT planes][free][npart2][h1g]
    u16* prodb = (u16*)attnR;
    u16* pl   = (u16*)(attnR + 8388608);
    u16* wqTh = pl;                u16* wqTl = pl + 262144;
    u16* wkTh = pl + 524288;       u16* wkTl = pl + 786432;
    u16* wvTh = pl + 1048576;      u16* wvTl = pl + 1310720;
    float* npart2 = attnR + 12582912;     // 1,048,576 f used
    u16* h1g = (u16*)(attnR + 14680064);  // 2,097,152 u16

    u16* u16b  = (u16*)(ws + 20103168);
    u16* w1hi  = u16b;                    // 131,072 u16
    u16* w2hi  = u16b + 262144;           // 131,072 u16
    u16* rw2hi = u16b + 524288;           // 32,768 u16
    u16* wouTh = u16b + 17367040;
    u16* wouTl = u16b + 17629184;         // end ~116 MB total ws

    k_preT<<<1920, 256, 0, stream>>>(aw1, aw2, pw2, wq, wk, wv, wout,
                                     canonical, pw1, pb1,
                                     w1hi, w2hi, rw2hi,
                                     wqTh, wqTl, wkTh, wkTl, wvTh, wvTl, wouTh, wouTl,
                                     nbr, h1g);
    k_projM<<<dim3(32, 8), 256, 0, stream>>>(query, key_in, value,
                                             wqTh, wqTl, wkTh, wkTl, wvTh, wvTl, Dws, Vws);
    k_attn<<<dim3(64, HH, BS), 256, 0, stream>>>(Dws, Vws, nbr, pb2, ab1, ab2,
                                                 w1hi, w2hi, rw2hi, h1g, prodb, npart2);
    k_normR<<<256, 256, 0, stream>>>(npart2, nrm);
    k_agg<<<dim3(64, HH, BS), 256, 0, stream>>>(prodb, nrm, aggb);
    k_outM<<<dim3(32, 8), 256, 0, stream>>>(aggb, wouTh, wouTl, bout, (float*)d_out);
}